// Round 2
// baseline (983.221 us; speedup 1.0000x reference)
//
#include <hip/hip_runtime.h>
#include <hip/hip_bf16.h>
#include <math.h>

#define B_  2
#define S_  2048
#define H_  1024
#define NH_ 4
#define DH_ 256

#define RT 32   // rows per block (main kernel)
#define JT 32   // cols per tile

// ---------------------------------------------------------------------------
// Kernel 1: gate projections.  gate_in = concat(q,k,v) along h (3H), kernels
// (3H, NH).  One block per (b,s); 256 threads reduce the 3072-length dots.
// Outputs: ig_pre[b][nh][s], logsig_fg[b][nh][s]
// ---------------------------------------------------------------------------
__global__ __launch_bounds__(256) void gates_kernel(
    const float* __restrict__ q, const float* __restrict__ k,
    const float* __restrict__ v,
    const float* __restrict__ igk, const float* __restrict__ igb,
    const float* __restrict__ fgk, const float* __restrict__ fgb,
    float* __restrict__ ig_pre, float* __restrict__ lsf) {
  int bs = blockIdx.x;
  int b = bs / S_, s = bs % S_;
  const float* qrow = q + ((size_t)b * S_ + s) * H_;
  const float* krow = k + ((size_t)b * S_ + s) * H_;
  const float* vrow = v + ((size_t)b * S_ + s) * H_;

  float accI[NH_] = {0.f, 0.f, 0.f, 0.f};
  float accF[NH_] = {0.f, 0.f, 0.f, 0.f};
  for (int h = threadIdx.x; h < H_; h += 256) {
    float qv = qrow[h], kv = krow[h], vv = vrow[h];
#pragma unroll
    for (int n = 0; n < NH_; ++n) {
      accI[n] += qv * igk[(size_t)h * NH_ + n]
               + kv * igk[(size_t)(H_ + h) * NH_ + n]
               + vv * igk[(size_t)(2 * H_ + h) * NH_ + n];
      accF[n] += qv * fgk[(size_t)h * NH_ + n]
               + kv * fgk[(size_t)(H_ + h) * NH_ + n]
               + vv * fgk[(size_t)(2 * H_ + h) * NH_ + n];
    }
  }
  // wave reduce (64 lanes)
#pragma unroll
  for (int n = 0; n < NH_; ++n) {
    for (int m = 1; m < 64; m <<= 1) {
      accI[n] += __shfl_xor(accI[n], m);
      accF[n] += __shfl_xor(accF[n], m);
    }
  }
  __shared__ float red[4][8];
  int wave = threadIdx.x >> 6;
  int lane = threadIdx.x & 63;
  if (lane == 0) {
#pragma unroll
    for (int n = 0; n < NH_; ++n) {
      red[wave][n] = accI[n];
      red[wave][4 + n] = accF[n];
    }
  }
  __syncthreads();
  if (threadIdx.x < 8) {
    int t = threadIdx.x;
    float sum = red[0][t] + red[1][t] + red[2][t] + red[3][t];
    if (t < 4) {
      int n = t;
      ig_pre[((size_t)(b * NH_ + n)) * S_ + s] = sum + igb[n];
    } else {
      int n = t - 4;
      float x = sum + fgb[n];
      // log_sigmoid, numerically stable
      float ls = (x >= 0.f) ? -log1pf(expf(-x)) : (x - log1pf(expf(x)));
      lsf[((size_t)(b * NH_ + n)) * S_ + s] = ls;
    }
  }
}

// ---------------------------------------------------------------------------
// Kernel 2: per-(b,nh) scan.  csum = inclusive cumsum(logsig_fg),
// a[j] = ig[j] - csum[j], M[j] = prefix max of a, floor[j] = exp(-(csum+M)).
// One wave (64 lanes) per sequence; chunked shfl_up scans.
// ---------------------------------------------------------------------------
__global__ __launch_bounds__(64) void scan_kernel(
    const float* __restrict__ ig_pre, const float* __restrict__ lsf,
    float* __restrict__ a_out, float* __restrict__ M_out,
    float* __restrict__ fl_out) {
  int hd = blockIdx.x;  // b*NH + nh
  int lane = threadIdx.x;
  const float* ig = ig_pre + (size_t)hd * S_;
  const float* ls = lsf + (size_t)hd * S_;
  float carry = 0.f;
  float mcarry = -INFINITY;
  for (int c = 0; c < S_ / 64; ++c) {
    int s = c * 64 + lane;
    float x = ls[s];
    for (int off = 1; off < 64; off <<= 1) {
      float t = __shfl_up(x, off);
      if (lane >= off) x += t;
    }
    float csum = carry + x;
    float a = ig[s] - csum;
    float y = a;
    for (int off = 1; off < 64; off <<= 1) {
      float t = __shfl_up(y, off);
      if (lane >= off) y = fmaxf(y, t);
    }
    float M = fmaxf(mcarry, y);
    a_out[(size_t)hd * S_ + s] = a;
    M_out[(size_t)hd * S_ + s] = M;
    fl_out[(size_t)hd * S_ + s] = expf(-(csum + M));
    carry = __shfl(csum, 63);
    mcarry = __shfl(M, 63);
  }
}

// ---------------------------------------------------------------------------
// Kernel 3: main tiled kernel.  Block = 256 threads = (32 rows) x (8 lanes).
// Thread (r, c8) owns row i = rt*32+r and dh chunks {4*(c8+8m)..+3}, m=0..7
// (stride-32-float interleave -> conflict-free b128 LDS reads).
// Per j-tile: stage K,V (32x256 f32 each) into LDS; dot-product with 8-lane
// shfl reduce; weight c = qk/16 * exp(a[j]-M[i]) (causal); accumulate row_sum
// and O.  Epilogue: normalizer, multihead layernorm, f32 store.
// ---------------------------------------------------------------------------
__global__ __launch_bounds__(256) void mlstm_main(
    const float* __restrict__ q, const float* __restrict__ k,
    const float* __restrict__ v,
    const float* __restrict__ a_arr, const float* __restrict__ M_arr,
    const float* __restrict__ fl_arr,
    const float* __restrict__ scale, float* __restrict__ out) {
  const int nrt = S_ / RT;                  // 64
  int bid = blockIdx.x;
  int rt = (nrt - 1) - (bid % nrt);         // long blocks first
  int hd = bid / nrt;                       // 0..7
  int b = hd >> 2, nh = hd & 3;

  int tid = threadIdx.x;
  int r = tid >> 3;       // 0..31
  int c8 = tid & 7;       // 0..7
  int i = rt * RT + r;    // global row

  const float* qrow = q + ((size_t)b * S_ + i) * H_ + nh * DH_;
  float4 q_reg[8];
#pragma unroll
  for (int m = 0; m < 8; ++m)
    q_reg[m] = reinterpret_cast<const float4*>(qrow)[c8 + 8 * m];

  float M_r = M_arr[(size_t)hd * S_ + i];
  float fl_r = fl_arr[(size_t)hd * S_ + i];

  float4 o_acc[8];
#pragma unroll
  for (int m = 0; m < 8; ++m) o_acc[m] = make_float4(0.f, 0.f, 0.f, 0.f);
  float row_sum = 0.f;

  __shared__ float k_lds[RT][DH_];
  __shared__ float v_lds[RT][DH_];
  __shared__ float aw[JT];

  const float qk_scale = 0.0625f;  // 1/sqrt(256)

  for (int jt = 0; jt <= rt; ++jt) {
    __syncthreads();
    int j0 = jt * JT;
    // stage K,V tile (each thread: 8 float4 per matrix, coalesced)
    for (int idx = tid; idx < RT * DH_ / 4; idx += 256) {
      int jr = idx >> 6;   // row in tile
      int c4 = idx & 63;   // float4 col
      const float4* kr = reinterpret_cast<const float4*>(
          k + ((size_t)b * S_ + j0 + jr) * H_ + nh * DH_);
      const float4* vr = reinterpret_cast<const float4*>(
          v + ((size_t)b * S_ + j0 + jr) * H_ + nh * DH_);
      reinterpret_cast<float4*>(k_lds[jr])[c4] = kr[c4];
      reinterpret_cast<float4*>(v_lds[jr])[c4] = vr[c4];
    }
    if (tid < JT) aw[tid] = a_arr[(size_t)hd * S_ + j0 + tid];
    __syncthreads();

    for (int jj = 0; jj < JT; ++jj) {
      const float4* krow4 = reinterpret_cast<const float4*>(k_lds[jj]);
      float part = 0.f;
#pragma unroll
      for (int m = 0; m < 8; ++m) {
        float4 k4 = krow4[c8 + 8 * m];
        part += q_reg[m].x * k4.x + q_reg[m].y * k4.y +
                q_reg[m].z * k4.z + q_reg[m].w * k4.w;
      }
      part += __shfl_xor(part, 1);
      part += __shfl_xor(part, 2);
      part += __shfl_xor(part, 4);
      int j = j0 + jj;
      float c = part * qk_scale * __expf(aw[jj] - M_r);
      c = (j <= i) ? c : 0.f;
      row_sum += c;
      const float4* vrow4 = reinterpret_cast<const float4*>(v_lds[jj]);
#pragma unroll
      for (int m = 0; m < 8; ++m) {
        float4 v4 = vrow4[c8 + 8 * m];
        o_acc[m].x += c * v4.x;
        o_acc[m].y += c * v4.y;
        o_acc[m].z += c * v4.z;
        o_acc[m].w += c * v4.w;
      }
    }
  }

  // normalizer
  float norm = fmaxf(fabsf(row_sum), fl_r) + 1e-6f;
  float inv = 1.f / norm;

  // layernorm over the 256 dh of this head (spread over 8 lanes x 32 vals)
  float s1 = 0.f, s2 = 0.f;
#pragma unroll
  for (int m = 0; m < 8; ++m) {
    o_acc[m].x *= inv; o_acc[m].y *= inv; o_acc[m].z *= inv; o_acc[m].w *= inv;
    s1 += o_acc[m].x + o_acc[m].y + o_acc[m].z + o_acc[m].w;
    s2 += o_acc[m].x * o_acc[m].x + o_acc[m].y * o_acc[m].y +
          o_acc[m].z * o_acc[m].z + o_acc[m].w * o_acc[m].w;
  }
  s1 += __shfl_xor(s1, 1); s2 += __shfl_xor(s2, 1);
  s1 += __shfl_xor(s1, 2); s2 += __shfl_xor(s2, 2);
  s1 += __shfl_xor(s1, 4); s2 += __shfl_xor(s2, 4);
  float mean = s1 * (1.f / DH_);
  float var = s2 * (1.f / DH_) - mean * mean;
  float rstd = rsqrtf(var + 1e-6f);

  float* orow = out + ((size_t)b * S_ + i) * H_ + nh * DH_;
#pragma unroll
  for (int m = 0; m < 8; ++m) {
    int d0 = 4 * (c8 + 8 * m);
    float4 st;
    st.x = (o_acc[m].x - mean) * rstd * scale[nh * DH_ + d0 + 0];
    st.y = (o_acc[m].y - mean) * rstd * scale[nh * DH_ + d0 + 1];
    st.z = (o_acc[m].z - mean) * rstd * scale[nh * DH_ + d0 + 2];
    st.w = (o_acc[m].w - mean) * rstd * scale[nh * DH_ + d0 + 3];
    *reinterpret_cast<float4*>(orow + d0) = st;
  }
}

// ---------------------------------------------------------------------------
extern "C" void kernel_launch(void* const* d_in, const int* in_sizes, int n_in,
                              void* d_out, int out_size, void* d_ws,
                              size_t ws_size, hipStream_t stream) {
  const float* q   = (const float*)d_in[0];
  const float* k   = (const float*)d_in[1];
  const float* v   = (const float*)d_in[2];
  const float* igk = (const float*)d_in[3];
  const float* igb = (const float*)d_in[4];
  const float* fgk = (const float*)d_in[5];
  const float* fgb = (const float*)d_in[6];
  const float* scl = (const float*)d_in[7];
  float* out = (float*)d_out;

  const size_t seq = (size_t)B_ * NH_ * S_;  // 16384
  float* ws = (float*)d_ws;
  float* ig_pre = ws;
  float* lsf    = ws + seq;
  float* a_arr  = ws + 2 * seq;
  float* M_arr  = ws + 3 * seq;
  float* fl_arr = ws + 4 * seq;

  gates_kernel<<<B_ * S_, 256, 0, stream>>>(q, k, v, igk, igb, fgk, fgb,
                                            ig_pre, lsf);
  scan_kernel<<<B_ * NH_, 64, 0, stream>>>(ig_pre, lsf, a_arr, M_arr, fl_arr);
  mlstm_main<<<B_ * NH_ * (S_ / RT), 256, 0, stream>>>(
      q, k, v, a_arr, M_arr, fl_arr, scl, out);
}

// Round 4
// 294.413 us; speedup vs baseline: 3.3396x; 3.3396x over previous
//
#include <hip/hip_runtime.h>
#include <hip/hip_bf16.h>
#include <math.h>

#define B_  2
#define S_  2048
#define H_  1024
#define NH_ 4
#define DH_ 256

typedef __attribute__((ext_vector_type(8))) short short8;
typedef __attribute__((ext_vector_type(2))) short short2v;
typedef __attribute__((ext_vector_type(4))) float f32x4;

static __device__ __forceinline__ short f2bf(float x) {
  __hip_bfloat16 h = __float2bfloat16(x);
  union { __hip_bfloat16 h; short s; } u;
  u.h = h;
  return u.s;
}

static __device__ __forceinline__ short8 pack8(const float4& a, const float4& b) {
  short8 t;
  t[0] = f2bf(a.x); t[1] = f2bf(a.y); t[2] = f2bf(a.z); t[3] = f2bf(a.w);
  t[4] = f2bf(b.x); t[5] = f2bf(b.y); t[6] = f2bf(b.z); t[7] = f2bf(b.w);
  return t;
}

// ---------------------------------------------------------------------------
// Kernel 1: gate projections (proven in round 2).
// ---------------------------------------------------------------------------
__global__ __launch_bounds__(256) void gates_kernel(
    const float* __restrict__ q, const float* __restrict__ k,
    const float* __restrict__ v,
    const float* __restrict__ igk, const float* __restrict__ igb,
    const float* __restrict__ fgk, const float* __restrict__ fgb,
    float* __restrict__ ig_pre, float* __restrict__ lsf) {
  int bs = blockIdx.x;
  int b = bs / S_, s = bs % S_;
  const float* qrow = q + ((size_t)b * S_ + s) * H_;
  const float* krow = k + ((size_t)b * S_ + s) * H_;
  const float* vrow = v + ((size_t)b * S_ + s) * H_;

  float accI[NH_] = {0.f, 0.f, 0.f, 0.f};
  float accF[NH_] = {0.f, 0.f, 0.f, 0.f};
  for (int h = threadIdx.x; h < H_; h += 256) {
    float qv = qrow[h], kv = krow[h], vv = vrow[h];
#pragma unroll
    for (int n = 0; n < NH_; ++n) {
      accI[n] += qv * igk[(size_t)h * NH_ + n]
               + kv * igk[(size_t)(H_ + h) * NH_ + n]
               + vv * igk[(size_t)(2 * H_ + h) * NH_ + n];
      accF[n] += qv * fgk[(size_t)h * NH_ + n]
               + kv * fgk[(size_t)(H_ + h) * NH_ + n]
               + vv * fgk[(size_t)(2 * H_ + h) * NH_ + n];
    }
  }
#pragma unroll
  for (int n = 0; n < NH_; ++n) {
    for (int m = 1; m < 64; m <<= 1) {
      accI[n] += __shfl_xor(accI[n], m);
      accF[n] += __shfl_xor(accF[n], m);
    }
  }
  __shared__ float red[4][8];
  int wave = threadIdx.x >> 6;
  int lane = threadIdx.x & 63;
  if (lane == 0) {
#pragma unroll
    for (int n = 0; n < NH_; ++n) {
      red[wave][n] = accI[n];
      red[wave][4 + n] = accF[n];
    }
  }
  __syncthreads();
  if (threadIdx.x < 8) {
    int t = threadIdx.x;
    float sum = red[0][t] + red[1][t] + red[2][t] + red[3][t];
    if (t < 4) {
      int n = t;
      ig_pre[((size_t)(b * NH_ + n)) * S_ + s] = sum + igb[n];
    } else {
      int n = t - 4;
      float x = sum + fgb[n];
      float ls = (x >= 0.f) ? -log1pf(expf(-x)) : (x - log1pf(expf(x)));
      lsf[((size_t)(b * NH_ + n)) * S_ + s] = ls;
    }
  }
}

// ---------------------------------------------------------------------------
// Kernel 2: per-(b,nh) scan (proven in round 2).
// ---------------------------------------------------------------------------
__global__ __launch_bounds__(64) void scan_kernel(
    const float* __restrict__ ig_pre, const float* __restrict__ lsf,
    float* __restrict__ a_out, float* __restrict__ M_out,
    float* __restrict__ fl_out) {
  int hd = blockIdx.x;
  int lane = threadIdx.x;
  const float* ig = ig_pre + (size_t)hd * S_;
  const float* ls = lsf + (size_t)hd * S_;
  float carry = 0.f;
  float mcarry = -INFINITY;
  for (int c = 0; c < S_ / 64; ++c) {
    int s = c * 64 + lane;
    float x = ls[s];
    for (int off = 1; off < 64; off <<= 1) {
      float t = __shfl_up(x, off);
      if (lane >= off) x += t;
    }
    float csum = carry + x;
    float a = ig[s] - csum;
    float y = a;
    for (int off = 1; off < 64; off <<= 1) {
      float t = __shfl_up(y, off);
      if (lane >= off) y = fmaxf(y, t);
    }
    float M = fmaxf(mcarry, y);
    a_out[(size_t)hd * S_ + s] = a;
    M_out[(size_t)hd * S_ + s] = M;
    fl_out[(size_t)hd * S_ + s] = expf(-(csum + M));
    carry = __shfl(csum, 63);
    mcarry = __shfl(M, 63);
  }
}

// ---------------------------------------------------------------------------
// Kernel 3: MFMA main kernel (single-buffered, no parity split, no asm DS).
//   grid = 8 (b,nh) x 32 row-tiles of 64 rows; block = 256 threads (4 waves).
//   wave w owns rows iw = i0 + 16w .. +15.
// LDS (shorts unless noted):
//   K  : [32 rows][256], 16B slots, phys_slot = slot ^ (row&7)      bytes [0,16384)
//   vT : addr = d*40 + (j ^ (((d>>4)&3)<<3)), d<256, j<32           bytes [16384,36864)
//   P  : per wave [16 rows][stride 40]                              bytes [36864,+4*1280)
// ---------------------------------------------------------------------------
#define KOFF 0
#define VOFF 16384
#define POFF 36864
#define SMEM_BYTES (36864 + 4 * 1280)

__global__ __launch_bounds__(256) void mlstm_mfma(
    const float* __restrict__ q, const float* __restrict__ k,
    const float* __restrict__ v,
    const float* __restrict__ a_arr, const float* __restrict__ M_arr,
    const float* __restrict__ fl_arr,
    const float* __restrict__ scale, float* __restrict__ out) {
  __shared__ __align__(16) char smem[SMEM_BYTES];

  const int bid = blockIdx.x;
  const int hd = bid >> 5;            // 0..7
  const int rtb = 31 - (bid & 31);    // long blocks first
  const int b = hd >> 2, nh = hd & 3;
  const int i0 = rtb * 64;

  const int tid = threadIdx.x;
  const int wave = tid >> 6;
  const int l = tid & 63;
  const int g = l >> 4;      // 0..3
  const int c16 = l & 15;    // 0..15
  const int iw = i0 + wave * 16;

  short* vt = reinterpret_cast<short*>(smem + VOFF);
  short* pb = reinterpret_cast<short*>(smem + POFF + wave * 1280);
  const short8* kb8 = reinterpret_cast<const short8*>(smem + KOFF);

  // ---- Q A-fragments: row = iw + c16, k-elems = 32c + 8g + e ----
  short8 qf[8];
  {
    const float* qp = q + ((size_t)b * S_ + (iw + c16)) * H_ + nh * DH_;
#pragma unroll
    for (int c = 0; c < 8; ++c) {
      int d0 = c * 32 + g * 8;
      float4 f0 = *reinterpret_cast<const float4*>(qp + d0);
      float4 f1 = *reinterpret_cast<const float4*>(qp + d0 + 4);
      qf[c] = pack8(f0, f1);
    }
  }
  float Mr[4], flr[4];
#pragma unroll
  for (int r = 0; r < 4; ++r) {
    Mr[r]  = M_arr[(size_t)hd * S_ + iw + 4 * g + r];
    flr[r] = fl_arr[(size_t)hd * S_ + iw + 4 * g + r];
  }

  f32x4 oa[16];
#pragma unroll
  for (int d = 0; d < 16; ++d) oa[d] = (f32x4){0.f, 0.f, 0.f, 0.f};
  float rs[4] = {0.f, 0.f, 0.f, 0.f};

  // staging maps
  const int sjk = tid >> 3;   // K row 0..31
  const int sck = tid & 7;    // K d-block of 32
  const int sjp = tid >> 4;   // V row-pair 0..15
  const int scv = tid & 15;   // V d-block of 16

  const float* kgb = k + (size_t)b * S_ * H_ + nh * DH_;
  const float* vgb = v + (size_t)b * S_ * H_ + nh * DH_;
  const float* agb = a_arr + (size_t)hd * S_;

  const int jtmaxB = (i0 + 63) >> 5;
  const int jtmaxW = (iw + 15) >> 5;

  for (int jt = 0; jt <= jtmaxB; ++jt) {
    const int j0 = jt * 32;
    __syncthreads();  // previous tile's readers done before we overwrite
    // ---- stage K: row-major, slot-XOR swizzle ----
    {
      const float* kp = kgb + (size_t)(j0 + sjk) * H_ + sck * 32;
      float4 kr[8];
#pragma unroll
      for (int u = 0; u < 8; ++u)
        kr[u] = *reinterpret_cast<const float4*>(kp + 4 * u);
      short8* krow8 = const_cast<short8*>(kb8) + sjk * 32;
#pragma unroll
      for (int u = 0; u < 4; ++u) {
        int phys = (4 * sck + u) ^ (sjk & 7);
        krow8[phys] = pack8(kr[2 * u], kr[2 * u + 1]);
      }
    }
    // ---- stage V transposed into vT ----
    {
      const float* vp0 = vgb + (size_t)(j0 + 2 * sjp) * H_ + scv * 16;
      const float* vp1 = vp0 + H_;
      float4 r0[4], r1[4];
#pragma unroll
      for (int u = 0; u < 4; ++u) {
        r0[u] = *reinterpret_cast<const float4*>(vp0 + 4 * u);
        r1[u] = *reinterpret_cast<const float4*>(vp1 + 4 * u);
      }
      const int jph = (2 * sjp) ^ ((scv & 3) << 3);
#pragma unroll
      for (int m = 0; m < 16; ++m) {
        int d = scv * 16 + m;
        short2v t;
        t[0] = f2bf(reinterpret_cast<const float*>(r0)[m]);
        t[1] = f2bf(reinterpret_cast<const float*>(r1)[m]);
        *reinterpret_cast<short2v*>(vt + d * 40 + jph) = t;
      }
    }
    __syncthreads();

    if (jt <= jtmaxW) {
      // ---- S = Q K^T (two 16-wide j sub-tiles) ----
      f32x4 sa0 = {0.f, 0.f, 0.f, 0.f}, sa1 = {0.f, 0.f, 0.f, 0.f};
#pragma unroll
      for (int c = 0; c < 8; ++c) {
        int row0 = c16, row1 = 16 + c16;
        int slot = 4 * c + g;
        short8 kf0 = kb8[row0 * 32 + (slot ^ (row0 & 7))];
        short8 kf1 = kb8[row1 * 32 + (slot ^ (row1 & 7))];
        sa0 = __builtin_amdgcn_mfma_f32_16x16x32_bf16(qf[c], kf0, sa0, 0, 0, 0);
        sa1 = __builtin_amdgcn_mfma_f32_16x16x32_bf16(qf[c], kf1, sa1, 0, 0, 0);
      }
      // ---- weights, causal mask, rowsum, P -> wave-private LDS ----
      float a0 = agb[j0 + c16];
      float a1 = agb[j0 + 16 + c16];
#pragma unroll
      for (int r = 0; r < 4; ++r) {
        int i = iw + 4 * g + r;
        float w0 = sa0[r] * 0.0625f * __expf(a0 - Mr[r]);
        if (j0 + c16 > i) w0 = 0.f;
        float w1 = sa1[r] * 0.0625f * __expf(a1 - Mr[r]);
        if (j0 + 16 + c16 > i) w1 = 0.f;
        rs[r] += w0 + w1;
        pb[(4 * g + r) * 40 + c16]      = f2bf(w0);
        pb[(4 * g + r) * 40 + 16 + c16] = f2bf(w1);
      }
      asm volatile("" ::: "memory");  // order P write before P read (same wave)
      short8 pa = *reinterpret_cast<const short8*>(pb + c16 * 40 + 8 * g);
      // ---- O += P V (16 d-chunks) ----
#pragma unroll
      for (int dq = 0; dq < 16; ++dq) {
        short8 vf = *reinterpret_cast<const short8*>(
            vt + (16 * dq + c16) * 40 + 8 * (g ^ (dq & 3)));
        oa[dq] = __builtin_amdgcn_mfma_f32_16x16x32_bf16(pa, vf, oa[dq], 0, 0, 0);
      }
    }
  }

  // ---- rowsum reduce across the 16-lane group ----
#pragma unroll
  for (int r = 0; r < 4; ++r) {
    rs[r] += __shfl_xor(rs[r], 1);
    rs[r] += __shfl_xor(rs[r], 2);
    rs[r] += __shfl_xor(rs[r], 4);
    rs[r] += __shfl_xor(rs[r], 8);
  }

  // ---- normalizer + multihead layernorm ----
  float inv[4];
#pragma unroll
  for (int r = 0; r < 4; ++r)
    inv[r] = 1.f / (fmaxf(fabsf(rs[r]), flr[r]) + 1e-6f);

  float s1[4] = {0.f, 0.f, 0.f, 0.f}, s2[4] = {0.f, 0.f, 0.f, 0.f};
#pragma unroll
  for (int dq = 0; dq < 16; ++dq)
#pragma unroll
    for (int r = 0; r < 4; ++r) {
      float x = oa[dq][r] * inv[r];
      oa[dq][r] = x;
      s1[r] += x;
      s2[r] += x * x;
    }
  float mean[4], rstd[4];
#pragma unroll
  for (int r = 0; r < 4; ++r) {
    s1[r] += __shfl_xor(s1[r], 1); s2[r] += __shfl_xor(s2[r], 1);
    s1[r] += __shfl_xor(s1[r], 2); s2[r] += __shfl_xor(s2[r], 2);
    s1[r] += __shfl_xor(s1[r], 4); s2[r] += __shfl_xor(s2[r], 4);
    s1[r] += __shfl_xor(s1[r], 8); s2[r] += __shfl_xor(s2[r], 8);
    mean[r] = s1[r] * (1.f / DH_);
    float var = s2[r] * (1.f / DH_) - mean[r] * mean[r];
    rstd[r] = rsqrtf(var + 1e-6f);
  }
#pragma unroll
  for (int dq = 0; dq < 16; ++dq) {
    float sc_d = scale[nh * DH_ + dq * 16 + c16];
#pragma unroll
    for (int r = 0; r < 4; ++r) {
      out[((size_t)b * S_ + iw + 4 * g + r) * H_ + nh * DH_ + dq * 16 + c16] =
          (oa[dq][r] - mean[r]) * rstd[r] * sc_d;
    }
  }
}

// ---------------------------------------------------------------------------
extern "C" void kernel_launch(void* const* d_in, const int* in_sizes, int n_in,
                              void* d_out, int out_size, void* d_ws,
                              size_t ws_size, hipStream_t stream) {
  const float* q   = (const float*)d_in[0];
  const float* k   = (const float*)d_in[1];
  const float* v   = (const float*)d_in[2];
  const float* igk = (const float*)d_in[3];
  const float* igb = (const float*)d_in[4];
  const float* fgk = (const float*)d_in[5];
  const float* fgb = (const float*)d_in[6];
  const float* scl = (const float*)d_in[7];
  float* out = (float*)d_out;

  const size_t seq = (size_t)B_ * NH_ * S_;
  float* ws = (float*)d_ws;
  float* ig_pre = ws;
  float* lsf    = ws + seq;
  float* a_arr  = ws + 2 * seq;
  float* M_arr  = ws + 3 * seq;
  float* fl_arr = ws + 4 * seq;

  gates_kernel<<<B_ * S_, 256, 0, stream>>>(q, k, v, igk, igb, fgk, fgb,
                                            ig_pre, lsf);
  scan_kernel<<<B_ * NH_, 64, 0, stream>>>(ig_pre, lsf, a_arr, M_arr, fl_arr);
  mlstm_mfma<<<B_ * NH_ * 32, 256, 0, stream>>>(
      q, k, v, a_arr, M_arr, fl_arr, scl, out);
}

// Round 6
// 270.100 us; speedup vs baseline: 3.6402x; 1.0900x over previous
//
#include <hip/hip_runtime.h>
#include <hip/hip_bf16.h>
#include <math.h>

#define B_  2
#define S_  2048
#define H_  1024
#define NH_ 4
#define DH_ 256

typedef __attribute__((ext_vector_type(8))) short short8;
typedef __attribute__((ext_vector_type(2))) short short2v;
typedef __attribute__((ext_vector_type(4))) float f32x4;

static __device__ __forceinline__ short f2bf(float x) {
  __hip_bfloat16 h = __float2bfloat16(x);
  union { __hip_bfloat16 h; short s; } u;
  u.h = h;
  return u.s;
}

static __device__ __forceinline__ short8 pack8(const float4& a, const float4& b) {
  short8 t;
  t[0] = f2bf(a.x); t[1] = f2bf(a.y); t[2] = f2bf(a.z); t[3] = f2bf(a.w);
  t[4] = f2bf(b.x); t[5] = f2bf(b.y); t[6] = f2bf(b.z); t[7] = f2bf(b.w);
  return t;
}

// ---------------------------------------------------------------------------
// Kernel 1: gate projections (proven in rounds 2/4).
// ---------------------------------------------------------------------------
__global__ __launch_bounds__(256) void gates_kernel(
    const float* __restrict__ q, const float* __restrict__ k,
    const float* __restrict__ v,
    const float* __restrict__ igk, const float* __restrict__ igb,
    const float* __restrict__ fgk, const float* __restrict__ fgb,
    float* __restrict__ ig_pre, float* __restrict__ lsf) {
  int bs = blockIdx.x;
  int b = bs / S_, s = bs % S_;
  const float* qrow = q + ((size_t)b * S_ + s) * H_;
  const float* krow = k + ((size_t)b * S_ + s) * H_;
  const float* vrow = v + ((size_t)b * S_ + s) * H_;

  float accI[NH_] = {0.f, 0.f, 0.f, 0.f};
  float accF[NH_] = {0.f, 0.f, 0.f, 0.f};
  for (int h = threadIdx.x; h < H_; h += 256) {
    float qv = qrow[h], kv = krow[h], vv = vrow[h];
#pragma unroll
    for (int n = 0; n < NH_; ++n) {
      accI[n] += qv * igk[(size_t)h * NH_ + n]
               + kv * igk[(size_t)(H_ + h) * NH_ + n]
               + vv * igk[(size_t)(2 * H_ + h) * NH_ + n];
      accF[n] += qv * fgk[(size_t)h * NH_ + n]
               + kv * fgk[(size_t)(H_ + h) * NH_ + n]
               + vv * fgk[(size_t)(2 * H_ + h) * NH_ + n];
    }
  }
#pragma unroll
  for (int n = 0; n < NH_; ++n) {
    for (int m = 1; m < 64; m <<= 1) {
      accI[n] += __shfl_xor(accI[n], m);
      accF[n] += __shfl_xor(accF[n], m);
    }
  }
  __shared__ float red[4][8];
  int wave = threadIdx.x >> 6;
  int lane = threadIdx.x & 63;
  if (lane == 0) {
#pragma unroll
    for (int n = 0; n < NH_; ++n) {
      red[wave][n] = accI[n];
      red[wave][4 + n] = accF[n];
    }
  }
  __syncthreads();
  if (threadIdx.x < 8) {
    int t = threadIdx.x;
    float sum = red[0][t] + red[1][t] + red[2][t] + red[3][t];
    if (t < 4) {
      int n = t;
      ig_pre[((size_t)(b * NH_ + n)) * S_ + s] = sum + igb[n];
    } else {
      int n = t - 4;
      float x = sum + fgb[n];
      float ls = (x >= 0.f) ? -log1pf(expf(-x)) : (x - log1pf(expf(x)));
      lsf[((size_t)(b * NH_ + n)) * S_ + s] = ls;
    }
  }
}

// ---------------------------------------------------------------------------
// Kernel 2: per-(b,nh) scan — in-register version.
// ---------------------------------------------------------------------------
__global__ __launch_bounds__(64) void scan_kernel(
    const float* __restrict__ ig_pre, const float* __restrict__ lsf,
    float* __restrict__ a_out, float* __restrict__ M_out,
    float* __restrict__ fl_out) {
  int hd = blockIdx.x;
  int lane = threadIdx.x;
  const float* ig = ig_pre + (size_t)hd * S_;
  const float* ls = lsf + (size_t)hd * S_;
  float xs[32], ys[32];
#pragma unroll
  for (int c = 0; c < 32; ++c) xs[c] = ls[c * 64 + lane];
#pragma unroll
  for (int c = 0; c < 32; ++c) ys[c] = ig[c * 64 + lane];

  float carry = 0.f;
  float mcarry = -INFINITY;
#pragma unroll
  for (int c = 0; c < 32; ++c) {
    int s = c * 64 + lane;
    float x = xs[c];
    for (int off = 1; off < 64; off <<= 1) {
      float t = __shfl_up(x, off);
      if (lane >= off) x += t;
    }
    float csum = carry + x;
    float a = ys[c] - csum;
    float y = a;
    for (int off = 1; off < 64; off <<= 1) {
      float t = __shfl_up(y, off);
      if (lane >= off) y = fmaxf(y, t);
    }
    float M = fmaxf(mcarry, y);
    a_out[(size_t)hd * S_ + s] = a;
    M_out[(size_t)hd * S_ + s] = M;
    fl_out[(size_t)hd * S_ + s] = expf(-(csum + M));
    carry = __shfl(csum, 63);
    mcarry = __shfl(M, 63);
  }
}

// ---------------------------------------------------------------------------
// Kernel 3: MFMA main kernel, T14-pipelined.
//   grid = 256: hd = bid&7 (XCD-affine), rtb = 31-(bid>>3); 64 rows/block.
//   block = 256 threads (4 waves), wave w owns rows iw = i0+16w .. +15.
// LDS (bytes):
//   K   [0,16384):        [32 j][256 d] bf16, 16B slots, phys = slot^(j&7)
//   V0  [16384,36864):    vT: elem(d,j) at short index d*40 + (j^(((d>>4)&3)<<3))
//   V1  [36864,57344):    second V buffer
//   P   [57344,62464):    per-wave [16][40] shorts
// Pipeline per tile: issue next global loads -> QK -> bar1 -> exp/P -> PV
//   -> ds_write next K (single buf, safe after bar1) + next V (other buf)
//   -> bar2.
// NOTE: never build an indexable array of LDS-derived pointers (gfx950
// "unsupported expression in static initializer"); select via byte offset.
// ---------------------------------------------------------------------------
#define KOFF 0
#define VOFF0 16384
#define VOFF1 36864
#define POFF 57344
#define SMEM_BYTES 62464

__global__ __launch_bounds__(256) void mlstm_mfma(
    const float* __restrict__ q, const float* __restrict__ k,
    const float* __restrict__ v,
    const float* __restrict__ a_arr, const float* __restrict__ M_arr,
    const float* __restrict__ fl_arr,
    const float* __restrict__ scale, float* __restrict__ out) {
  __shared__ __align__(16) char smem[SMEM_BYTES];

  const int bid = blockIdx.x;
  const int hd = bid & 7;             // same head -> same XCD (L2 locality)
  const int rtb = 31 - (bid >> 3);
  const int b = hd >> 2, nh = hd & 3;
  const int i0 = rtb * 64;

  const int tid = threadIdx.x;
  const int wave = tid >> 6;
  const int l = tid & 63;
  const int g = l >> 4;      // 0..3
  const int c16 = l & 15;    // 0..15
  const int iw = i0 + wave * 16;

  const short8* kb8 = reinterpret_cast<const short8*>(smem + KOFF);
  short* pb = reinterpret_cast<short*>(smem + POFF + wave * 1280);

  // ---- Q A-fragments: row = iw + c16, k-elems = 32c + 8g + e ----
  short8 qf[8];
  {
    const float* qp = q + ((size_t)b * S_ + (iw + c16)) * H_ + nh * DH_;
#pragma unroll
    for (int c = 0; c < 8; ++c) {
      int d0 = c * 32 + g * 8;
      float4 f0 = *reinterpret_cast<const float4*>(qp + d0);
      float4 f1 = *reinterpret_cast<const float4*>(qp + d0 + 4);
      qf[c] = pack8(f0, f1);
    }
  }
  float Mr[4], flr[4];
#pragma unroll
  for (int r = 0; r < 4; ++r) {
    Mr[r]  = M_arr[(size_t)hd * S_ + iw + 4 * g + r];
    flr[r] = fl_arr[(size_t)hd * S_ + iw + 4 * g + r];
  }

  f32x4 oa[16];
#pragma unroll
  for (int d = 0; d < 16; ++d) oa[d] = (f32x4){0.f, 0.f, 0.f, 0.f};
  float rs[4] = {0.f, 0.f, 0.f, 0.f};

  // staging maps
  const int sjk = tid >> 3;   // K row 0..31
  const int sck = tid & 7;    // K d-block of 32
  const int sjp = tid >> 4;   // V row-pair 0..15
  const int scv = tid & 15;   // V d-stripe base

  const float* kgb = k + (size_t)b * S_ * H_ + nh * DH_;
  const float* vgb = v + (size_t)b * S_ * H_ + nh * DH_;
  const float* agb = a_arr + (size_t)hd * S_;

  const int jtmaxB = 2 * rtb + 1;            // inclusive
  const int jtmaxW = (iw + 15) >> 5;         // inclusive, per wave

  float4 kr[8];
  float va[16], vb[16];

  auto stage_load = [&](int jt) {
    const float* kp = kgb + (size_t)(jt * 32 + sjk) * H_ + sck * 32;
#pragma unroll
    for (int u = 0; u < 8; ++u)
      kr[u] = *reinterpret_cast<const float4*>(kp + 4 * u);
    const float* vp0 = vgb + (size_t)(jt * 32 + 2 * sjp) * H_;
    const float* vp1 = vp0 + H_;
#pragma unroll
    for (int m = 0; m < 16; ++m) {
      va[m] = vp0[scv + 16 * m];
      vb[m] = vp1[scv + 16 * m];
    }
  };

  auto write_k = [&]() {
    short8* krow8 = const_cast<short8*>(kb8) + sjk * 32;
#pragma unroll
    for (int u = 0; u < 4; ++u) {
      int phys = (4 * sck + u) ^ (sjk & 7);
      krow8[phys] = pack8(kr[2 * u], kr[2 * u + 1]);
    }
  };

  auto write_v = [&](int buf) {
    short* vt = reinterpret_cast<short*>(smem + (buf ? VOFF1 : VOFF0));
#pragma unroll
    for (int m = 0; m < 16; ++m) {
      int d = scv + 16 * m;                 // d-stripe: bank varies with scv
      int jph = (2 * sjp) ^ ((m & 3) << 3); // (d>>4)&3 == m&3
      short2v t;
      t[0] = f2bf(va[m]);
      t[1] = f2bf(vb[m]);
      *reinterpret_cast<short2v*>(vt + d * 40 + jph) = t;
    }
  };

  // prologue: tile 0
  stage_load(0);
  write_k();
  write_v(0);
  __syncthreads();

  for (int jt = 0; jt <= jtmaxB; ++jt) {
    const int cur = jt & 1;
    const bool last = (jt == jtmaxB);
    const bool active = (jt <= jtmaxW);

    if (!last) stage_load(jt + 1);  // globals in flight during compute

    // ---- S = Q K^T (two 16-wide j sub-tiles) ----
    f32x4 sa0 = {0.f, 0.f, 0.f, 0.f}, sa1 = {0.f, 0.f, 0.f, 0.f};
    if (active) {
#pragma unroll
      for (int c = 0; c < 8; ++c) {
        int row0 = c16, row1 = 16 + c16;
        int slot = 4 * c + g;
        short8 kf0 = kb8[row0 * 32 + (slot ^ (row0 & 7))];
        short8 kf1 = kb8[row1 * 32 + (slot ^ (row1 & 7))];
        sa0 = __builtin_amdgcn_mfma_f32_16x16x32_bf16(qf[c], kf0, sa0, 0, 0, 0);
        sa1 = __builtin_amdgcn_mfma_f32_16x16x32_bf16(qf[c], kf1, sa1, 0, 0, 0);
      }
    }
    __syncthreads();  // bar1: all waves done reading K (and prev V writes ok)

    if (active) {
      const int j0 = jt * 32;
      // ---- weights, causal mask, rowsum, P -> wave-private LDS ----
      float a0 = agb[j0 + c16];
      float a1 = agb[j0 + 16 + c16];
#pragma unroll
      for (int r = 0; r < 4; ++r) {
        int i = iw + 4 * g + r;
        float w0 = sa0[r] * 0.0625f * __expf(a0 - Mr[r]);
        if (j0 + c16 > i) w0 = 0.f;
        float w1 = sa1[r] * 0.0625f * __expf(a1 - Mr[r]);
        if (j0 + 16 + c16 > i) w1 = 0.f;
        rs[r] += w0 + w1;
        pb[(4 * g + r) * 40 + c16]      = f2bf(w0);
        pb[(4 * g + r) * 40 + 16 + c16] = f2bf(w1);
      }
      asm volatile("" ::: "memory");
      short8 pa = *reinterpret_cast<const short8*>(pb + c16 * 40 + 8 * g);
      // ---- O += P V ----
      const short* vt = reinterpret_cast<const short*>(smem + (cur ? VOFF1 : VOFF0));
#pragma unroll
      for (int dq = 0; dq < 16; ++dq) {
        short8 vf = *reinterpret_cast<const short8*>(
            vt + (16 * dq + c16) * 40 + 8 * (g ^ (dq & 3)));
        oa[dq] = __builtin_amdgcn_mfma_f32_16x16x32_bf16(pa, vf, oa[dq], 0, 0, 0);
      }
    }

    if (!last) {
      write_k();            // safe: all QK reads of this tile passed bar1
      write_v(cur ^ 1);
    }
    __syncthreads();  // bar2: next tile staged
  }

  // ---- rowsum reduce across the 16-lane group ----
#pragma unroll
  for (int r = 0; r < 4; ++r) {
    rs[r] += __shfl_xor(rs[r], 1);
    rs[r] += __shfl_xor(rs[r], 2);
    rs[r] += __shfl_xor(rs[r], 4);
    rs[r] += __shfl_xor(rs[r], 8);
  }

  // ---- normalizer + multihead layernorm ----
  float inv[4];
#pragma unroll
  for (int r = 0; r < 4; ++r)
    inv[r] = 1.f / (fmaxf(fabsf(rs[r]), flr[r]) + 1e-6f);

  float s1[4] = {0.f, 0.f, 0.f, 0.f}, s2[4] = {0.f, 0.f, 0.f, 0.f};
#pragma unroll
  for (int dq = 0; dq < 16; ++dq)
#pragma unroll
    for (int r = 0; r < 4; ++r) {
      float x = oa[dq][r] * inv[r];
      oa[dq][r] = x;
      s1[r] += x;
      s2[r] += x * x;
    }
  float mean[4], rstd[4];
#pragma unroll
  for (int r = 0; r < 4; ++r) {
    s1[r] += __shfl_xor(s1[r], 1); s2[r] += __shfl_xor(s2[r], 1);
    s1[r] += __shfl_xor(s1[r], 2); s2[r] += __shfl_xor(s2[r], 2);
    s1[r] += __shfl_xor(s1[r], 4); s2[r] += __shfl_xor(s2[r], 4);
    s1[r] += __shfl_xor(s1[r], 8); s2[r] += __shfl_xor(s2[r], 8);
    mean[r] = s1[r] * (1.f / DH_);
    float var = s2[r] * (1.f / DH_) - mean[r] * mean[r];
    rstd[r] = rsqrtf(var + 1e-6f);
  }
#pragma unroll
  for (int dq = 0; dq < 16; ++dq) {
    float sc_d = scale[nh * DH_ + dq * 16 + c16];
#pragma unroll
    for (int r = 0; r < 4; ++r) {
      out[((size_t)b * S_ + iw + 4 * g + r) * H_ + nh * DH_ + dq * 16 + c16] =
          (oa[dq][r] - mean[r]) * rstd[r] * sc_d;
    }
  }
}

// ---------------------------------------------------------------------------
extern "C" void kernel_launch(void* const* d_in, const int* in_sizes, int n_in,
                              void* d_out, int out_size, void* d_ws,
                              size_t ws_size, hipStream_t stream) {
  const float* q   = (const float*)d_in[0];
  const float* k   = (const float*)d_in[1];
  const float* v   = (const float*)d_in[2];
  const float* igk = (const float*)d_in[3];
  const float* igb = (const float*)d_in[4];
  const float* fgk = (const float*)d_in[5];
  const float* fgb = (const float*)d_in[6];
  const float* scl = (const float*)d_in[7];
  float* out = (float*)d_out;

  const size_t seq = (size_t)B_ * NH_ * S_;
  float* ws = (float*)d_ws;
  float* ig_pre = ws;
  float* lsf    = ws + seq;
  float* a_arr  = ws + 2 * seq;
  float* M_arr  = ws + 3 * seq;
  float* fl_arr = ws + 4 * seq;

  gates_kernel<<<B_ * S_, 256, 0, stream>>>(q, k, v, igk, igb, fgk, fgb,
                                            ig_pre, lsf);
  scan_kernel<<<B_ * NH_, 64, 0, stream>>>(ig_pre, lsf, a_arr, M_arr, fl_arr);
  mlstm_mfma<<<B_ * NH_ * 32, 256, 0, stream>>>(
      q, k, v, a_arr, M_arr, fl_arr, scl, out);
}

// Round 7
// 227.432 us; speedup vs baseline: 4.3231x; 1.1876x over previous
//
#include <hip/hip_runtime.h>
#include <hip/hip_bf16.h>
#include <math.h>

#define B_  2
#define S_  2048
#define H_  1024
#define NH_ 4
#define DH_ 256

typedef __attribute__((ext_vector_type(8))) short short8;
typedef __attribute__((ext_vector_type(2))) short short2v;
typedef __attribute__((ext_vector_type(4))) float f32x4;

static __device__ __forceinline__ short f2bf(float x) {
  __hip_bfloat16 h = __float2bfloat16(x);
  union { __hip_bfloat16 h; short s; } u;
  u.h = h;
  return u.s;
}

static __device__ __forceinline__ short8 pack8(const float4& a, const float4& b) {
  short8 t;
  t[0] = f2bf(a.x); t[1] = f2bf(a.y); t[2] = f2bf(a.z); t[3] = f2bf(a.w);
  t[4] = f2bf(b.x); t[5] = f2bf(b.y); t[6] = f2bf(b.z); t[7] = f2bf(b.w);
  return t;
}

// ---------------------------------------------------------------------------
// Kernel 1: gate projections (proven in rounds 2/4/6).
// ---------------------------------------------------------------------------
__global__ __launch_bounds__(256) void gates_kernel(
    const float* __restrict__ q, const float* __restrict__ k,
    const float* __restrict__ v,
    const float* __restrict__ igk, const float* __restrict__ igb,
    const float* __restrict__ fgk, const float* __restrict__ fgb,
    float* __restrict__ ig_pre, float* __restrict__ lsf) {
  int bs = blockIdx.x;
  int b = bs / S_, s = bs % S_;
  const float* qrow = q + ((size_t)b * S_ + s) * H_;
  const float* krow = k + ((size_t)b * S_ + s) * H_;
  const float* vrow = v + ((size_t)b * S_ + s) * H_;

  float accI[NH_] = {0.f, 0.f, 0.f, 0.f};
  float accF[NH_] = {0.f, 0.f, 0.f, 0.f};
  for (int h = threadIdx.x; h < H_; h += 256) {
    float qv = qrow[h], kv = krow[h], vv = vrow[h];
#pragma unroll
    for (int n = 0; n < NH_; ++n) {
      accI[n] += qv * igk[(size_t)h * NH_ + n]
               + kv * igk[(size_t)(H_ + h) * NH_ + n]
               + vv * igk[(size_t)(2 * H_ + h) * NH_ + n];
      accF[n] += qv * fgk[(size_t)h * NH_ + n]
               + kv * fgk[(size_t)(H_ + h) * NH_ + n]
               + vv * fgk[(size_t)(2 * H_ + h) * NH_ + n];
    }
  }
#pragma unroll
  for (int n = 0; n < NH_; ++n) {
    for (int m = 1; m < 64; m <<= 1) {
      accI[n] += __shfl_xor(accI[n], m);
      accF[n] += __shfl_xor(accF[n], m);
    }
  }
  __shared__ float red[4][8];
  int wave = threadIdx.x >> 6;
  int lane = threadIdx.x & 63;
  if (lane == 0) {
#pragma unroll
    for (int n = 0; n < NH_; ++n) {
      red[wave][n] = accI[n];
      red[wave][4 + n] = accF[n];
    }
  }
  __syncthreads();
  if (threadIdx.x < 8) {
    int t = threadIdx.x;
    float sum = red[0][t] + red[1][t] + red[2][t] + red[3][t];
    if (t < 4) {
      int n = t;
      ig_pre[((size_t)(b * NH_ + n)) * S_ + s] = sum + igb[n];
    } else {
      int n = t - 4;
      float x = sum + fgb[n];
      float ls = (x >= 0.f) ? -log1pf(expf(-x)) : (x - log1pf(expf(x)));
      lsf[((size_t)(b * NH_ + n)) * S_ + s] = ls;
    }
  }
}

// ---------------------------------------------------------------------------
// Kernel 2: per-(b,nh) scan — in-register version (proven round 6).
// ---------------------------------------------------------------------------
__global__ __launch_bounds__(64) void scan_kernel(
    const float* __restrict__ ig_pre, const float* __restrict__ lsf,
    float* __restrict__ a_out, float* __restrict__ M_out,
    float* __restrict__ fl_out) {
  int hd = blockIdx.x;
  int lane = threadIdx.x;
  const float* ig = ig_pre + (size_t)hd * S_;
  const float* ls = lsf + (size_t)hd * S_;
  float xs[32], ys[32];
#pragma unroll
  for (int c = 0; c < 32; ++c) xs[c] = ls[c * 64 + lane];
#pragma unroll
  for (int c = 0; c < 32; ++c) ys[c] = ig[c * 64 + lane];

  float carry = 0.f;
  float mcarry = -INFINITY;
#pragma unroll
  for (int c = 0; c < 32; ++c) {
    int s = c * 64 + lane;
    float x = xs[c];
    for (int off = 1; off < 64; off <<= 1) {
      float t = __shfl_up(x, off);
      if (lane >= off) x += t;
    }
    float csum = carry + x;
    float a = ys[c] - csum;
    float y = a;
    for (int off = 1; off < 64; off <<= 1) {
      float t = __shfl_up(y, off);
      if (lane >= off) y = fmaxf(y, t);
    }
    float M = fmaxf(mcarry, y);
    a_out[(size_t)hd * S_ + s] = a;
    M_out[(size_t)hd * S_ + s] = M;
    fl_out[(size_t)hd * S_ + s] = expf(-(csum + M));
    carry = __shfl(csum, 63);
    mcarry = __shfl(M, 63);
  }
}

// ---------------------------------------------------------------------------
// Kernel 3: MFMA main kernel, split-parity for load balance + 2 blocks/CU.
//   grid = 512. bid<256:  p=0, hd=bid&7,      rtb=31-(bid>>3)  (work desc)
//              bid>=256: p=1, hd=(bid-256)&7, rtb=(bid-256)>>3 (work asc)
//   -> each CU gets one long + one short block (round-robin), ~33 tiles, and
//      both co-resident (LDS 2x61KB, VGPR<=256) -> 8 waves/CU latency hiding.
//   Block (hd,rtb,p) computes j-tiles jt = p, p+2, ... <= 2*rtb+1 and writes
//   RAW partial O (f32) + partial rowsum; combine_kernel finishes.
//   p=0 partial O -> d_out (used as scratch); p=1 partial O -> ws.
// LDS layout unchanged from round 6 (proven correct).
// ---------------------------------------------------------------------------
#define KOFF 0
#define VOFF0 16384
#define VOFF1 36864
#define POFF 57344
#define SMEM_BYTES 62464

__global__ __launch_bounds__(256) void mlstm_mfma(
    const float* __restrict__ q, const float* __restrict__ k,
    const float* __restrict__ v,
    const float* __restrict__ a_arr, const float* __restrict__ M_arr,
    float* __restrict__ rsA, float* __restrict__ rsB,
    float* __restrict__ poB, float* __restrict__ out) {
  __shared__ __align__(16) char smem[SMEM_BYTES];

  const int bid = blockIdx.x;
  int p, hd, rtb;
  if (bid < 256) { p = 0; hd = bid & 7; rtb = 31 - (bid >> 3); }
  else           { p = 1; hd = (bid - 256) & 7; rtb = (bid - 256) >> 3; }
  const int b = hd >> 2, nh = hd & 3;
  const int i0 = rtb * 64;

  const int tid = threadIdx.x;
  const int wave = tid >> 6;
  const int l = tid & 63;
  const int g = l >> 4;      // 0..3
  const int c16 = l & 15;    // 0..15
  const int iw = i0 + wave * 16;

  const short8* kb8 = reinterpret_cast<const short8*>(smem + KOFF);
  short* pb = reinterpret_cast<short*>(smem + POFF + wave * 1280);

  // ---- Q A-fragments: row = iw + c16, k-elems = 32c + 8g + e ----
  short8 qf[8];
  {
    const float* qp = q + ((size_t)b * S_ + (iw + c16)) * H_ + nh * DH_;
#pragma unroll
    for (int c = 0; c < 8; ++c) {
      int d0 = c * 32 + g * 8;
      float4 f0 = *reinterpret_cast<const float4*>(qp + d0);
      float4 f1 = *reinterpret_cast<const float4*>(qp + d0 + 4);
      qf[c] = pack8(f0, f1);
    }
  }
  float Mr[4];
#pragma unroll
  for (int r = 0; r < 4; ++r)
    Mr[r] = M_arr[(size_t)hd * S_ + iw + 4 * g + r];

  f32x4 oa[16];
#pragma unroll
  for (int d = 0; d < 16; ++d) oa[d] = (f32x4){0.f, 0.f, 0.f, 0.f};
  float rs[4] = {0.f, 0.f, 0.f, 0.f};

  // staging maps
  const int sjk = tid >> 3;   // K row 0..31
  const int sck = tid & 7;    // K d-block of 32
  const int sjp = tid >> 4;   // V row-pair 0..15
  const int scv = tid & 15;   // V d-stripe base

  const float* kgb = k + (size_t)b * S_ * H_ + nh * DH_;
  const float* vgb = v + (size_t)b * S_ * H_ + nh * DH_;
  const float* agb = a_arr + (size_t)hd * S_;

  const int ntiles = rtb + 1;                // tiles of this parity
  const int jtmaxW = (iw + 15) >> 5;         // causal cap per wave

  float4 kr[8];
  float va[16], vb[16];

  auto stage_load = [&](int jt) {
    const float* kp = kgb + (size_t)(jt * 32 + sjk) * H_ + sck * 32;
#pragma unroll
    for (int u = 0; u < 8; ++u)
      kr[u] = *reinterpret_cast<const float4*>(kp + 4 * u);
    const float* vp0 = vgb + (size_t)(jt * 32 + 2 * sjp) * H_;
    const float* vp1 = vp0 + H_;
#pragma unroll
    for (int m = 0; m < 16; ++m) {
      va[m] = vp0[scv + 16 * m];
      vb[m] = vp1[scv + 16 * m];
    }
  };

  auto write_k = [&]() {
    short8* krow8 = const_cast<short8*>(kb8) + sjk * 32;
#pragma unroll
    for (int u = 0; u < 4; ++u) {
      int phys = (4 * sck + u) ^ (sjk & 7);
      krow8[phys] = pack8(kr[2 * u], kr[2 * u + 1]);
    }
  };

  auto write_v = [&](int buf) {
    short* vt = reinterpret_cast<short*>(smem + (buf ? VOFF1 : VOFF0));
#pragma unroll
    for (int m = 0; m < 16; ++m) {
      int d = scv + 16 * m;
      int jph = (2 * sjp) ^ ((m & 3) << 3);
      short2v t;
      t[0] = f2bf(va[m]);
      t[1] = f2bf(vb[m]);
      *reinterpret_cast<short2v*>(vt + d * 40 + jph) = t;
    }
  };

  // prologue: first tile of this parity
  stage_load(p);
  write_k();
  write_v(0);
  __syncthreads();

  for (int n = 0; n < ntiles; ++n) {
    const int jt = 2 * n + p;
    const int cur = n & 1;
    const bool last = (n == ntiles - 1);
    const bool active = (jt <= jtmaxW);

    if (!last) stage_load(jt + 2);  // globals in flight during compute

    // ---- S = Q K^T (two 16-wide j sub-tiles) ----
    f32x4 sa0 = {0.f, 0.f, 0.f, 0.f}, sa1 = {0.f, 0.f, 0.f, 0.f};
    if (active) {
#pragma unroll
      for (int c = 0; c < 8; ++c) {
        int row0 = c16, row1 = 16 + c16;
        int slot = 4 * c + g;
        short8 kf0 = kb8[row0 * 32 + (slot ^ (row0 & 7))];
        short8 kf1 = kb8[row1 * 32 + (slot ^ (row1 & 7))];
        sa0 = __builtin_amdgcn_mfma_f32_16x16x32_bf16(qf[c], kf0, sa0, 0, 0, 0);
        sa1 = __builtin_amdgcn_mfma_f32_16x16x32_bf16(qf[c], kf1, sa1, 0, 0, 0);
      }
    }
    __syncthreads();  // bar1: all waves done reading K

    if (active) {
      const int j0 = jt * 32;
      float a0 = agb[j0 + c16];
      float a1 = agb[j0 + 16 + c16];
#pragma unroll
      for (int r = 0; r < 4; ++r) {
        int i = iw + 4 * g + r;
        float w0 = sa0[r] * 0.0625f * __expf(a0 - Mr[r]);
        if (j0 + c16 > i) w0 = 0.f;
        float w1 = sa1[r] * 0.0625f * __expf(a1 - Mr[r]);
        if (j0 + 16 + c16 > i) w1 = 0.f;
        rs[r] += w0 + w1;
        pb[(4 * g + r) * 40 + c16]      = f2bf(w0);
        pb[(4 * g + r) * 40 + 16 + c16] = f2bf(w1);
      }
      asm volatile("" ::: "memory");
      short8 pa = *reinterpret_cast<const short8*>(pb + c16 * 40 + 8 * g);
      const short* vt = reinterpret_cast<const short*>(smem + (cur ? VOFF1 : VOFF0));
#pragma unroll
      for (int dq = 0; dq < 16; ++dq) {
        short8 vf = *reinterpret_cast<const short8*>(
            vt + (16 * dq + c16) * 40 + 8 * (g ^ (dq & 3)));
        oa[dq] = __builtin_amdgcn_mfma_f32_16x16x32_bf16(pa, vf, oa[dq], 0, 0, 0);
      }
    }

    if (!last) {
      write_k();
      write_v(cur ^ 1);
    }
    __syncthreads();  // bar2: next tile staged
  }

  // ---- rowsum reduce across the 16-lane group ----
#pragma unroll
  for (int r = 0; r < 4; ++r) {
    rs[r] += __shfl_xor(rs[r], 1);
    rs[r] += __shfl_xor(rs[r], 2);
    rs[r] += __shfl_xor(rs[r], 4);
    rs[r] += __shfl_xor(rs[r], 8);
  }

  // ---- write partials (no normalizer / LN here) ----
  float* rsP = p ? rsB : rsA;
  if (c16 == 0) {
#pragma unroll
    for (int r = 0; r < 4; ++r)
      rsP[hd * S_ + iw + 4 * g + r] = rs[r];
  }
  if (p == 0) {
#pragma unroll
    for (int dq = 0; dq < 16; ++dq)
#pragma unroll
      for (int r = 0; r < 4; ++r)
        out[((size_t)b * S_ + iw + 4 * g + r) * H_ + nh * DH_ + dq * 16 + c16] =
            oa[dq][r];
  } else {
#pragma unroll
    for (int dq = 0; dq < 16; ++dq)
#pragma unroll
      for (int r = 0; r < 4; ++r)
        poB[((size_t)(hd * S_ + iw + 4 * g + r)) * DH_ + dq * 16 + c16] =
            oa[dq][r];
  }
}

// ---------------------------------------------------------------------------
// Kernel 4: combine partials -> normalizer + multihead layernorm -> out.
//   1 wave per row (4 waves/block, grid 4096). Lane owns 4 consecutive d.
// ---------------------------------------------------------------------------
__global__ __launch_bounds__(256) void combine_kernel(
    const float* __restrict__ poB, const float* __restrict__ rsA,
    const float* __restrict__ rsB, const float* __restrict__ fl_arr,
    const float* __restrict__ scale, float* __restrict__ out) {
  int ridx = blockIdx.x * 4 + (threadIdx.x >> 6);
  int lane = threadIdx.x & 63;
  int hd = ridx >> 11, i = ridx & 2047;
  int b = hd >> 2, nh = hd & 3;

  float* op = out + ((size_t)b * S_ + i) * H_ + nh * DH_ + lane * 4;
  float4 a4 = *reinterpret_cast<const float4*>(op);
  float4 b4 = *reinterpret_cast<const float4*>(
      poB + ((size_t)(hd * S_ + i)) * DH_ + lane * 4);

  float rsum = rsA[hd * S_ + i] + rsB[hd * S_ + i];
  float fl = fl_arr[(size_t)hd * S_ + i];
  float inv = 1.f / (fmaxf(fabsf(rsum), fl) + 1e-6f);

  float o0 = (a4.x + b4.x) * inv;
  float o1 = (a4.y + b4.y) * inv;
  float o2 = (a4.z + b4.z) * inv;
  float o3 = (a4.w + b4.w) * inv;

  float s1 = o0 + o1 + o2 + o3;
  float s2 = o0 * o0 + o1 * o1 + o2 * o2 + o3 * o3;
#pragma unroll
  for (int m = 1; m < 64; m <<= 1) {
    s1 += __shfl_xor(s1, m);
    s2 += __shfl_xor(s2, m);
  }
  float mean = s1 * (1.f / DH_);
  float var = s2 * (1.f / DH_) - mean * mean;
  float rstd = rsqrtf(var + 1e-6f);

  const float* scp = scale + nh * DH_ + lane * 4;
  float4 res;
  res.x = (o0 - mean) * rstd * scp[0];
  res.y = (o1 - mean) * rstd * scp[1];
  res.z = (o2 - mean) * rstd * scp[2];
  res.w = (o3 - mean) * rstd * scp[3];
  *reinterpret_cast<float4*>(op) = res;
}

// ---------------------------------------------------------------------------
extern "C" void kernel_launch(void* const* d_in, const int* in_sizes, int n_in,
                              void* d_out, int out_size, void* d_ws,
                              size_t ws_size, hipStream_t stream) {
  const float* q   = (const float*)d_in[0];
  const float* k   = (const float*)d_in[1];
  const float* v   = (const float*)d_in[2];
  const float* igk = (const float*)d_in[3];
  const float* igb = (const float*)d_in[4];
  const float* fgk = (const float*)d_in[5];
  const float* fgb = (const float*)d_in[6];
  const float* scl = (const float*)d_in[7];
  float* out = (float*)d_out;

  const size_t seq = (size_t)B_ * NH_ * S_;  // 16384
  float* ws = (float*)d_ws;
  float* ig_pre = ws;
  float* lsf    = ws + seq;
  float* a_arr  = ws + 2 * seq;
  float* M_arr  = ws + 3 * seq;
  float* fl_arr = ws + 4 * seq;
  float* rsA    = ws + 5 * seq;
  float* rsB    = ws + 6 * seq;
  float* poB    = ws + 7 * seq;   // 8*2048*256 floats = 16.8 MB

  gates_kernel<<<B_ * S_, 256, 0, stream>>>(q, k, v, igk, igb, fgk, fgb,
                                            ig_pre, lsf);
  scan_kernel<<<B_ * NH_, 64, 0, stream>>>(ig_pre, lsf, a_arr, M_arr, fl_arr);
  mlstm_mfma<<<512, 256, 0, stream>>>(q, k, v, a_arr, M_arr,
                                      rsA, rsB, poB, out);
  combine_kernel<<<B_ * NH_ * S_ / 4, 256, 0, stream>>>(
      poB, rsA, rsB, fl_arr, scl, out);
}